// Round 4
// baseline (541.788 us; speedup 1.0000x reference)
//
#include <hip/hip_runtime.h>
#include <stdint.h>

typedef unsigned short u16;
typedef __bf16 bf8 __attribute__((ext_vector_type(8)));
typedef float f32x4 __attribute__((ext_vector_type(4)));

#define SEQ 2048
#define HIDDEN 4096
#define DQKV 6144   // 48 heads * 128
#define HD 128

// async global->LDS, 16B/lane. LDS dest is wave-uniform base + lane*16 (m104/m108);
// all staging layouts below are laid out so lane l's element lands at base + l*16B.
#define GLOAD_LDS16(g, l)                                                            \
    __builtin_amdgcn_global_load_lds((const __attribute__((address_space(1))) void*)(g), \
                                     (__attribute__((address_space(3))) void*)(l), 16, 0, 0)

__device__ __forceinline__ u16 f2bf(float f) {
    union { float f; unsigned u; } v{f};
    unsigned r = (v.u + 0x7fff + ((v.u >> 16) & 1)) >> 16;
    return (u16)r;
}
__device__ __forceinline__ float bf2f(u16 b) {
    union { unsigned u; float f; } v;
    v.u = ((unsigned)b) << 16;
    return v.f;
}

// ---------------- pre-pass kernels ----------------

__global__ void convert_bf16_kernel(const float* __restrict__ in, u16* __restrict__ out) {
    int i = (blockIdx.x * 256 + threadIdx.x) * 4;
    float4 v = *(const float4*)(in + i);
    u16 o[4] = {f2bf(v.x), f2bf(v.y), f2bf(v.z), f2bf(v.w)};
    *(uint2*)(out + i) = *(uint2*)o;
}

// in fp32 [K][N] -> out bf16 [N][K]
__global__ void transpose_w_kernel(const float* __restrict__ in, u16* __restrict__ out, int K, int N) {
    __shared__ u16 tile[64][65];
    int tn = N >> 6;
    int bk = blockIdx.x / tn, bn = blockIdx.x % tn;
    int k0 = bk * 64, n0 = bn * 64;
    int c = threadIdx.x & 63, r0 = threadIdx.x >> 6;
#pragma unroll
    for (int r = r0; r < 64; r += 4)
        tile[r][c] = f2bf(in[(size_t)(k0 + r) * N + n0 + c]);
    __syncthreads();
#pragma unroll
    for (int r = r0; r < 64; r += 4)
        out[(size_t)(n0 + r) * K + k0 + c] = tile[c][r];
}

// RoPE in-place on Q/K heads (0..39) of xqkv [2048][6144]
__global__ void rope_kernel(u16* __restrict__ x) {
    const int row = blockIdx.x / 10, hg = blockIdx.x % 10;
    const int head = hg * 4 + (threadIdx.x >> 6), j = threadIdx.x & 63;
    u16* p = x + (size_t)row * DQKV + head * HD + j;
    float x1 = bf2f(p[0]), x2 = bf2f(p[64]);
    float inv = exp2f(-(float)j * 0.20762050593045952f); // log2(10000)/64
    float s, c;
    sincosf((float)row * inv, &s, &c);
    p[0] = f2bf(x1 * c - x2 * s);
    p[64] = f2bf(x1 * s + x2 * c);
}

// V heads (40..47) of xqkv [2048][6144] -> VT [8][128][2048]
__global__ void transpose_v_kernel(const u16* __restrict__ xqkv, u16* __restrict__ vt) {
    __shared__ u16 tile[64][65];
    int h = blockIdx.x >> 6;
    int t = blockIdx.x & 63;
    int s0 = (t >> 1) * 64, d0 = (t & 1) * 64;
    int c = threadIdx.x & 63, r0 = threadIdx.x >> 6;
    const u16* src = xqkv + (40 + h) * HD + d0;
#pragma unroll
    for (int r = r0; r < 64; r += 4)
        tile[r][c] = src[(size_t)(s0 + r) * DQKV + c];
    __syncthreads();
    u16* dst = vt + ((size_t)h * HD + d0) * SEQ + s0;
#pragma unroll
    for (int r = r0; r < 64; r += 4)
        dst[(size_t)r * SEQ + c] = tile[c][r];
}

// ---------------- GEMM: C[M][*] = A[M][4096] * BT[N][4096]^T ----------------
// 16x16x32 MFMA with the round-2 EMPIRICALLY ZERO-CONFLICT fragment read
// pattern (row = frag*16+l15, col byte = (q4*16)^((l15&7)<<4); the 32x32
// variant of round 3 conflicted 1e7/dispatch -- reverted, open question).
// Grid exactly 256 blocks (1/CU), 8 waves as 2(m) x 4(n); wave tile 128 x WN*16.
// MODE 0: 256x192 (8x32 grid), bf16 out stride 6144. MODE 1: 256x128 (8x32),
// f32 out stride 4096.
// LDS: 2 buffers x [A BM rows | B BN rows] x 128 B rows. Storage swizzle:
// logical (r,c16B) at phys c ^ (r&7), realized by pre-permuting the global
// source column (rule #21); verified conflict-free in round 2.
// NEW this round -- software-pipelined schedule, 2 barriers per K-tile:
//   tile t: [areg/breg for cluster 0 prefetched at end of prev boundary]
//     cluster c: issue ds_reads for cluster c+1 -> setprio(1) -> 12 MFMA on
//     cluster c's registers -> setprio(0).  NO explicit lgkmcnt, NO barrier:
//     the compiler emits counted lgkmcnt before each MFMA group (m97), so
//     reads for c+1 overlap the MFMA pipe of cluster c.
//   barrier (all waves done reading buf[cur]) -> stage tile t+2 into buf[cur]
//   -> counted vmcnt(NL) (t+1 landed; t+2's NL loads stay in flight) ->
//   barrier -> prefetch B + A-pair-0 of tile t+1 from buf[cur^1].
template <int BM, int BN, int MODE>
__global__ __launch_bounds__(512, 2) void gemmp_kernel(const u16* __restrict__ A,
                                                       const u16* __restrict__ BT,
                                                       u16* __restrict__ Cbf,
                                                       float* __restrict__ Cf) {
    constexpr int WM = BM / 32;          // m-frags per wave (8)
    constexpr int WN = BN / 64;          // n-frags per wave (3 or 2)
    constexpr int NC = WM / 2;           // clusters per K-tile (4)
    constexpr int NLA = BM / 64, NLB = BN / 64, NL = NLA + NLB;   // 7 or 6
    constexpr int NBN = ((MODE == 0) ? DQKV : HIDDEN) / BN;
    constexpr int CSTR = (MODE == 0) ? DQKV : HIDDEN;
    constexpr int NT = 64;               // K / 64
    __shared__ __align__(16) u16 lds[2][(BM + BN) * 64];

    const int tid = threadIdx.x;
    const int w = tid >> 6, l = tid & 63, l15 = l & 15, q4 = l >> 4;
    const int wm = w >> 2, wn = w & 3;
    const int bm = blockIdx.x / NBN, bn = blockIdx.x % NBN;

    // staging: thread tid fills phys bytes [line*8192 + tid*16, +16)
    // = logical row line*64 + tid/8, col ((tid&7)^((tid>>3)&7))*16 (swizzled src)
    const int srow = tid >> 3;
    const int scol = ((tid & 7) ^ ((tid >> 3) & 7)) << 4;
    const char* spA[NLA];
    const char* spB[NLB];
#pragma unroll
    for (int L = 0; L < NLA; ++L)
        spA[L] = (const char*)(A + (size_t)(bm * BM + L * 64 + srow) * 4096) + scol;
#pragma unroll
    for (int L = 0; L < NLB; ++L)
        spB[L] = (const char*)(BT + (size_t)(bn * BN + L * 64 + srow) * 4096) + scol;

#define STG_A(L, tt, b) GLOAD_LDS16(spA[L] + (size_t)(tt) * 128, &lds[b][(L) * 4096 + w * 512])
#define STG_B(L, tt, b) GLOAD_LDS16(spB[L] + (size_t)(tt) * 128, &lds[b][BM * 64 + (L) * 4096 + w * 512])

    // prologue: stage tiles 0 and 1, wait for tile 0 only (NL of tile 1 in flight)
#pragma unroll
    for (int L = 0; L < NLA; ++L) STG_A(L, 0, 0);
#pragma unroll
    for (int L = 0; L < NLB; ++L) STG_B(L, 0, 0);
#pragma unroll
    for (int L = 0; L < NLA; ++L) STG_A(L, 1, 1);
#pragma unroll
    for (int L = 0; L < NLB; ++L) STG_B(L, 1, 1);
    if constexpr (NL == 7) asm volatile("s_waitcnt vmcnt(7)" ::: "memory");
    else                   asm volatile("s_waitcnt vmcnt(6)" ::: "memory");
    asm volatile("s_barrier" ::: "memory");

    // read-side swizzle (round-2 verified zero-conflict pattern)
    const int c0x = (q4 * 16) ^ ((l15 & 7) << 4);
    const int c1x = c0x ^ 64;

    f32x4 acc[WM][WN] = {};
    bf8 breg[WN][2];
    bf8 areg[2][2][2];   // [pipe parity][frag-in-pair][ks]; all indices static

#define LD_B(b)                                                              \
    do {                                                                     \
        _Pragma("unroll") for (int nf = 0; nf < WN; ++nf) {                  \
            const char* rp = (const char*)&lds[b][BM * 64]                   \
                             + (wn * (WN * 16) + nf * 16 + l15) * 128;       \
            breg[nf][0] = *(const bf8*)(rp + c0x);                           \
            breg[nf][1] = *(const bf8*)(rp + c1x);                           \
        }                                                                    \
    } while (0)
#define LD_APAIR(cc, b)                                                      \
    do {                                                                     \
        _Pragma("unroll") for (int j = 0; j < 2; ++j) {                      \
            const char* rp = (const char*)&lds[b][0]                         \
                             + (wm * (BM / 2) + ((cc) * 2 + j) * 16 + l15) * 128; \
            areg[(cc) & 1][j][0] = *(const bf8*)(rp + c0x);                  \
            areg[(cc) & 1][j][1] = *(const bf8*)(rp + c1x);                  \
        }                                                                    \
    } while (0)

    // initial register prefetch from buffer 0
    LD_B(0);
    LD_APAIR(0, 0);

#pragma unroll 1
    for (int t = 0; t < NT; ++t) {
        const int cur = t & 1;
#pragma unroll
        for (int c = 0; c < NC; ++c) {
            if (c < NC - 1) LD_APAIR(c + 1, cur);   // overlap with cluster c MFMA
            __builtin_amdgcn_s_setprio(1);
#pragma unroll
            for (int j = 0; j < 2; ++j)
#pragma unroll
                for (int nf = 0; nf < WN; ++nf)
#pragma unroll
                    for (int ks = 0; ks < 2; ++ks)
                        acc[c * 2 + j][nf] = __builtin_amdgcn_mfma_f32_16x16x32_bf16(
                            areg[c & 1][j][ks], breg[nf][ks], acc[c * 2 + j][nf], 0, 0, 0);
            __builtin_amdgcn_s_setprio(0);
        }
        if (t == NT - 1) break;
        // all waves done reading buf[cur] (MFMAs consumed the reads)
        asm volatile("s_barrier" ::: "memory");
        if (t < NT - 2) {
#pragma unroll
            for (int L = 0; L < NLA; ++L) STG_A(L, t + 2, cur);
#pragma unroll
            for (int L = 0; L < NLB; ++L) STG_B(L, t + 2, cur);
            if constexpr (NL == 7) asm volatile("s_waitcnt vmcnt(7)" ::: "memory");
            else                   asm volatile("s_waitcnt vmcnt(6)" ::: "memory");
        } else {
            asm volatile("s_waitcnt vmcnt(0)" ::: "memory");
        }
        // tile t+1's buffer is fully staged and visible
        asm volatile("s_barrier" ::: "memory");
        LD_B(cur ^ 1);
        LD_APAIR(0, cur ^ 1);
    }
#undef LD_B
#undef LD_APAIR
#undef STG_A
#undef STG_B

    const int rowb = bm * BM + wm * (BM / 2);
    const int colb = bn * BN + wn * (WN * 16);
#pragma unroll
    for (int mf = 0; mf < WM; ++mf)
#pragma unroll
        for (int nf = 0; nf < WN; ++nf)
#pragma unroll
            for (int r = 0; r < 4; ++r) {
                const int row = rowb + mf * 16 + q4 * 4 + r;
                const int col = colb + nf * 16 + l15;
                if constexpr (MODE == 0)
                    Cbf[(size_t)row * CSTR + col] = f2bf(acc[mf][nf][r]);
                else
                    Cf[(size_t)row * CSTR + col] = acc[mf][nf][r];
            }
}

// ---------------- flash attention ----------------
// grid: 512 = 16 q-tiles * 32 heads. block 256 = 4 waves, each wave owns 32 Q rows.
// No running max (scores bounded: |s|<~20 -> exp2 stays in fp32/bf16 range), so
// softmax = unnormalized p=exp2(s*cs), per-lane row-sum accumulated in registers,
// single shuffle-reduce + normalize at the end.
#define PSTR 72   // P row stride in shorts: 64 cols + 8 pad (2-way bank alias = free)
__global__ __launch_bounds__(256) void attn_kernel(const u16* __restrict__ xqkv,
                                                   const u16* __restrict__ vt,
                                                   u16* __restrict__ aw) {
    // smem layout (shorts): [0,8192) K [4][64][32]; [8192,16384) V [2][128][32];
    // [16384,16384+128*PSTR) P [128][PSTR].  Q staged once at [0,16384) then reused.
    __shared__ __align__(16) u16 sm[16384 + 128 * PSTR];
    const int tid = threadIdx.x, w = tid >> 6, l = tid & 63, l15 = l & 15, q4 = l >> 4;
    const int qh = blockIdx.x & 31;
    const int qslot = blockIdx.x >> 5;
    // complementary pairing: blocks b and b+256 get qt summing to 15 (tail balance)
    const int qt = (qslot < 8) ? qslot : 23 - qslot;
    const int kh = qh >> 2;

    { // stage Q tile: [ks=w][row 128][32], async
        const u16* gq = xqkv + (size_t)(qt * 128 + (l >> 2)) * DQKV + qh * HD + w * 32 + (l & 3) * 8;
#pragma unroll
        for (int i = 0; i < 8; ++i)
            GLOAD_LDS16(gq + (size_t)i * 16 * DQKV, &sm[w * 4096 + i * 512]);
    }
    __syncthreads();
    bf8 qf[4][2];
#pragma unroll
    for (int ks = 0; ks < 4; ++ks)
#pragma unroll
        for (int mt = 0; mt < 2; ++mt)
            qf[ks][mt] = *(const bf8*)&sm[ks * 4096 + (w * 32 + mt * 16 + l15) * 32 + q4 * 8];
    __syncthreads();

    f32x4 O[2][8] = {};
    float plrow[2][4] = {};   // per-lane unnormalized row-sum partials

    u16* ldsK = sm;
    u16* ldsV = sm + 8192;
    u16* ldsP = sm + 16384;
    const int nkt = 2 * qt + 2;
    const float cs = 0.12751744f; // (1/sqrt(128)) * log2(e)

    const u16* gk_base = xqkv + (32 + kh) * HD + w * 32 + (l & 3) * 8;
    const u16* gv_base = vt + (size_t)kh * HD * SEQ + (size_t)((w & 1) * 64 + (l >> 2)) * SEQ + (w >> 1) * 32 + (l & 3) * 8;

    for (int kt = 0; kt < nkt; ++kt) {
        { // stage K: wave w owns k-chunk ks=w  (async, lane-contiguous)
            const u16* gk = gk_base + (size_t)(kt * 64 + (l >> 2)) * DQKV;
#pragma unroll
            for (int i = 0; i < 4; ++i)
                GLOAD_LDS16(gk + (size_t)i * 16 * DQKV, ldsK + w * 2048 + i * 512);
        }
        { // stage V^T: wave w owns pk=w>>1, d-half=(w&1)*64
            const u16* gv = gv_base + kt * 64;
#pragma unroll
            for (int i = 0; i < 4; ++i)
                GLOAD_LDS16(gv + (size_t)i * 16 * SEQ, ldsV + (w >> 1) * 4096 + (w & 1) * 2048 + i * 512);
        }
        __syncthreads();   // drains vmcnt

        // S = Q K^T
        f32x4 S[2][4] = {};
#pragma unroll
        for (int ks = 0; ks < 4; ++ks) {
            bf8 kf[4];
#pragma unroll
            for (int nt = 0; nt < 4; ++nt)
                kf[nt] = *(const bf8*)&ldsK[ks * 2048 + (nt * 16 + l15) * 32 + q4 * 8];
#pragma unroll
            for (int mt = 0; mt < 2; ++mt)
#pragma unroll
                for (int nt = 0; nt < 4; ++nt)
                    S[mt][nt] = __builtin_amdgcn_mfma_f32_16x16x32_bf16(qf[ks][mt], kf[nt], S[mt][nt], 0, 0, 0);
        }

        const bool domask = (kt >= 2 * qt);
#pragma unroll
        for (int mt = 0; mt < 2; ++mt)
#pragma unroll
            for (int r = 0; r < 4; ++r) {
                const int row = qt * 128 + w * 32 + mt * 16 + q4 * 4 + r;
#pragma unroll
                for (int nt = 0; nt < 4; ++nt) {
                    float t = S[mt][nt][r] * cs;
                    if (domask && (kt * 64 + nt * 16 + l15 > row)) t = -1e30f;
                    float p = exp2f(t);
                    plrow[mt][r] += p;
                    ldsP[(w * 32 + mt * 16 + q4 * 4 + r) * PSTR + nt * 16 + l15] = f2bf(p);
                }
            }

        // O += P V   (P rows are wave-private: no barrier needed)
#pragma unroll
        for (int pk = 0; pk < 2; ++pk) {
            bf8 pf[2], vf[8];
#pragma unroll
            for (int mt = 0; mt < 2; ++mt)
                pf[mt] = *(const bf8*)&ldsP[(w * 32 + mt * 16 + l15) * PSTR + pk * 32 + q4 * 8];
#pragma unroll
            for (int nt = 0; nt < 8; ++nt)
                vf[nt] = *(const bf8*)&ldsV[pk * 4096 + (nt * 16 + l15) * 32 + q4 * 8];
#pragma unroll
            for (int mt = 0; mt < 2; ++mt)
#pragma unroll
                for (int nt = 0; nt < 8; ++nt)
                    O[mt][nt] = __builtin_amdgcn_mfma_f32_16x16x32_bf16(pf[mt], vf[nt], O[mt][nt], 0, 0, 0);
        }
        __syncthreads();   // all waves done reading K/V/P before next stage
    }

#pragma unroll
    for (int mt = 0; mt < 2; ++mt)
#pragma unroll
        for (int r = 0; r < 4; ++r) {
            float ls = plrow[mt][r];   // row-sum lives across the 16 lanes of this q4 group
#pragma unroll
            for (int off = 1; off <= 8; off <<= 1)
                ls += __shfl_xor(ls, off, 64);
            const float linv = 1.0f / ls;
            const int row = qt * 128 + w * 32 + mt * 16 + q4 * 4 + r;
#pragma unroll
            for (int nt = 0; nt < 8; ++nt)
                aw[(size_t)row * 4096 + qh * HD + nt * 16 + l15] = f2bf(O[mt][nt][r] * linv);
        }
}

// ---------------- launch ----------------

extern "C" void kernel_launch(void* const* d_in, const int* in_sizes, int n_in,
                              void* d_out, int out_size, void* d_ws, size_t ws_size,
                              hipStream_t stream) {
    const float* hs = (const float*)d_in[0];
    const float* wqkv = (const float*)d_in[1];
    const float* wo = (const float*)d_in[2];
    float* out = (float*)d_out;

    char* ws = (char*)d_ws;
    const size_t oHbf = 0;
    const size_t oWqkvT = oHbf + (size_t)SEQ * HIDDEN * 2;          // 16.78 MB
    const size_t oWoT = oWqkvT + (size_t)DQKV * HIDDEN * 2;         // +50.33 MB
    const size_t oXQKV = oWoT + (size_t)HIDDEN * HIDDEN * 2;        // +33.55 MB
    const size_t oVT = oXQKV + (size_t)SEQ * DQKV * 2;              // +25.17 MB
    const size_t oAW = oVT + (size_t)8 * HD * SEQ * 2;              // +4.19 MB
    const size_t total = oAW + (size_t)SEQ * HIDDEN * 2;            // +16.78 MB = 146.8 MB
    if (ws_size < total) return;

    u16* Hbf = (u16*)(ws + oHbf);
    u16* WqkvT = (u16*)(ws + oWqkvT);
    u16* WoT = (u16*)(ws + oWoT);
    u16* XQKV = (u16*)(ws + oXQKV);
    u16* VT = (u16*)(ws + oVT);
    u16* AW = (u16*)(ws + oAW);

    convert_bf16_kernel<<<(SEQ * HIDDEN) / 1024, 256, 0, stream>>>(hs, Hbf);
    transpose_w_kernel<<<(HIDDEN / 64) * (DQKV / 64), 256, 0, stream>>>(wqkv, WqkvT, HIDDEN, DQKV);
    transpose_w_kernel<<<(HIDDEN / 64) * (HIDDEN / 64), 256, 0, stream>>>(wo, WoT, HIDDEN, HIDDEN);
    gemmp_kernel<256, 192, 0><<<256, 512, 0, stream>>>(Hbf, WqkvT, XQKV, nullptr);  // 8x32 grid
    rope_kernel<<<SEQ * 10, 256, 0, stream>>>(XQKV);
    transpose_v_kernel<<<8 * 64, 256, 0, stream>>>(XQKV, VT);
    attn_kernel<<<512, 256, 0, stream>>>(XQKV, VT, AW);
    gemmp_kernel<256, 128, 1><<<256, 512, 0, stream>>>(AW, WoT, nullptr, out);      // 8x32 grid
}

// Round 5
// 523.318 us; speedup vs baseline: 1.0353x; 1.0353x over previous
//
#include <hip/hip_runtime.h>
#include <stdint.h>

typedef unsigned short u16;
typedef __bf16 bf8 __attribute__((ext_vector_type(8)));
typedef float f32x4 __attribute__((ext_vector_type(4)));

#define SEQ 2048
#define HIDDEN 4096
#define DQKV 6144   // 48 heads * 128
#define HD 128

// async global->LDS, 16B/lane. LDS dest is wave-uniform base + lane*16 (m104/m108);
// all staging layouts below are laid out so lane l's element lands at base + l*16B.
#define GLOAD_LDS16(g, l)                                                            \
    __builtin_amdgcn_global_load_lds((const __attribute__((address_space(1))) void*)(g), \
                                     (__attribute__((address_space(3))) void*)(l), 16, 0, 0)

__device__ __forceinline__ u16 f2bf(float f) {
    union { float f; unsigned u; } v{f};
    unsigned r = (v.u + 0x7fff + ((v.u >> 16) & 1)) >> 16;
    return (u16)r;
}
__device__ __forceinline__ float bf2f(u16 b) {
    union { unsigned u; float f; } v;
    v.u = ((unsigned)b) << 16;
    return v.f;
}

// ---------------- pre-pass kernels ----------------

__global__ void convert_bf16_kernel(const float* __restrict__ in, u16* __restrict__ out) {
    int i = (blockIdx.x * 256 + threadIdx.x) * 4;
    float4 v = *(const float4*)(in + i);
    u16 o[4] = {f2bf(v.x), f2bf(v.y), f2bf(v.z), f2bf(v.w)};
    *(uint2*)(out + i) = *(uint2*)o;
}

// in fp32 [K][N] -> out bf16 [N][K]
__global__ void transpose_w_kernel(const float* __restrict__ in, u16* __restrict__ out, int K, int N) {
    __shared__ u16 tile[64][65];
    int tn = N >> 6;
    int bk = blockIdx.x / tn, bn = blockIdx.x % tn;
    int k0 = bk * 64, n0 = bn * 64;
    int c = threadIdx.x & 63, r0 = threadIdx.x >> 6;
#pragma unroll
    for (int r = r0; r < 64; r += 4)
        tile[r][c] = f2bf(in[(size_t)(k0 + r) * N + n0 + c]);
    __syncthreads();
#pragma unroll
    for (int r = r0; r < 64; r += 4)
        out[(size_t)(n0 + r) * K + k0 + c] = tile[c][r];
}

// RoPE in-place on Q/K heads (0..39) of xqkv [2048][6144]
__global__ void rope_kernel(u16* __restrict__ x) {
    const int row = blockIdx.x / 10, hg = blockIdx.x % 10;
    const int head = hg * 4 + (threadIdx.x >> 6), j = threadIdx.x & 63;
    u16* p = x + (size_t)row * DQKV + head * HD + j;
    float x1 = bf2f(p[0]), x2 = bf2f(p[64]);
    float inv = exp2f(-(float)j * 0.20762050593045952f); // log2(10000)/64
    float s, c;
    sincosf((float)row * inv, &s, &c);
    p[0] = f2bf(x1 * c - x2 * s);
    p[64] = f2bf(x1 * s + x2 * c);
}

// V heads (40..47) of xqkv [2048][6144] -> VT [8][128][2048]
__global__ void transpose_v_kernel(const u16* __restrict__ xqkv, u16* __restrict__ vt) {
    __shared__ u16 tile[64][65];
    int h = blockIdx.x >> 6;
    int t = blockIdx.x & 63;
    int s0 = (t >> 1) * 64, d0 = (t & 1) * 64;
    int c = threadIdx.x & 63, r0 = threadIdx.x >> 6;
    const u16* src = xqkv + (40 + h) * HD + d0;
#pragma unroll
    for (int r = r0; r < 64; r += 4)
        tile[r][c] = src[(size_t)(s0 + r) * DQKV + c];
    __syncthreads();
    u16* dst = vt + ((size_t)h * HD + d0) * SEQ + s0;
#pragma unroll
    for (int r = r0; r < 64; r += 4)
        dst[(size_t)r * SEQ + c] = tile[c][r];
}

// ---------------- GEMM: C[M][*] = A[M][4096] * BT[N][4096]^T ----------------
// Round-2 structure (best measured: 108 us, 0 bank conflicts) + NEW: T1
// XCD-aware 2D chunking. HW dispatch round-robins blockIdx over 8 XCDs
// (xcd = blockIdx%8); we give each XCD a contiguous 4(bm) x 8(bn) sub-grid so
// its 32 blocks share operand panels: per-XCD per-K-step working set = 4
// A-tiles + 8 B-tiles (~320 KB, fits 4 MiB L2). L3->L2 operand traffic drops
// 918->164 MB (MODE0) / 786->131 MB (MODE1). Theory: all three prior schedules
// pinned at ~8 TB/s L2-fill with MfmaUtil 35-40% => delivery-locality-bound,
// not schedule-bound.
// MODE 0: 256x192 tile (8x32 grid), bf16 out stride 6144.
// MODE 1: 128x256 tile (16x16 grid), f32 out stride 4096.
// LDS: 2 buffers x [A BM rows | B BN rows] x 64 cols bf16, 128-byte rows.
// Swizzle (T2): logical (r,c16B) at phys c ^ (r&7), realized by pre-permuting
// the global source column (rule #21); verified conflict-free (round 2).
// Per K-tile: 4 phases, each {stage-issue || ds_read A-frag pair -> barrier ->
// lgkmcnt(0) -> setprio(1) -> MFMA cluster -> setprio(0) -> barrier}. N-side
// fragments are read once (phase 0) and held in registers for the whole K-tile.
// Staging of tile t+2 goes into the CURRENT buffer as regions die: B lines at
// p1 (B read only in p0), early-dead A lines at p2, rest at the boundary, then
// counted vmcnt(NL) (7 or 6, never 0 in steady state) + barrier.
template <int BM, int BN, int MODE>
__global__ __launch_bounds__(512, 2) void gemm8p_kernel(const u16* __restrict__ A,
                                                        const u16* __restrict__ BT,
                                                        u16* __restrict__ Cbf,
                                                        float* __restrict__ Cf) {
    constexpr int WM = BM / 32;          // m-frags per wave
    constexpr int WN = BN / 64;          // n-frags per wave
    constexpr int MP = WM / 4;           // m-frags per phase
    constexpr int NLA = BM / 64, NLB = BN / 64, NL = NLA + NLB;
    constexpr int NBN = ((MODE == 0) ? DQKV : HIDDEN) / BN;
    constexpr int NBM = SEQ / BM;
    constexpr int CSTR = (MODE == 0) ? DQKV : HIDDEN;
    constexpr int NT = 64;               // K / 64
    static_assert(NBM * NBN == 256, "grid must be exactly 256 blocks");
    __shared__ __align__(16) u16 lds[2][(BM + BN) * 64];

    const int tid = threadIdx.x;
    const int w = tid >> 6, l = tid & 63, l15 = l & 15, q4 = l >> 4;
    const int wm = w >> 2, wn = w & 3;

    // T1: XCD-aware 2D chunking (xcd = blockIdx%8 round-robin assumption).
    // Each XCD owns a 4(bm) x 8(bn) chunk; bijective on both grid shapes.
    const int xcd = blockIdx.x & 7, wi = blockIdx.x >> 3;
    int bm, bn;
    if constexpr (NBN == 32) {           // 8 x 32 grid (MODE 0)
        bm = (xcd >> 2) * 4 + (wi >> 3);
        bn = (xcd & 3) * 8 + (wi & 7);
    } else {                             // 16 x 16 grid (MODE 1)
        bm = (xcd & 3) * 4 + (wi >> 3);
        bn = (xcd >> 2) * 8 + (wi & 7);
    }

    // staging: thread tid fills phys bytes [line*8192 + tid*16, +16) of a region
    // = logical row line*64 + tid/8, col ((tid&7)^((tid>>3)&7))*16 (swizzled src)
    const int srow = tid >> 3;
    const int scol = ((tid & 7) ^ ((tid >> 3) & 7)) << 4;
    const char* spA[NLA];
    const char* spB[NLB];
#pragma unroll
    for (int L = 0; L < NLA; ++L)
        spA[L] = (const char*)(A + (size_t)(bm * BM + L * 64 + srow) * 4096) + scol;
#pragma unroll
    for (int L = 0; L < NLB; ++L)
        spB[L] = (const char*)(BT + (size_t)(bn * BN + L * 64 + srow) * 4096) + scol;

#define STG_A(L, tt, b) GLOAD_LDS16(spA[L] + (size_t)(tt) * 128, &lds[b][(L) * 4096 + w * 512])
#define STG_B(L, tt, b) GLOAD_LDS16(spB[L] + (size_t)(tt) * 128, &lds[b][BM * 64 + (L) * 4096 + w * 512])

    // prologue: stage tiles 0 and 1, wait for tile 0 only (NL of tile 1 in flight)
#pragma unroll
    for (int L = 0; L < NLA; ++L) STG_A(L, 0, 0);
#pragma unroll
    for (int L = 0; L < NLB; ++L) STG_B(L, 0, 0);
#pragma unroll
    for (int L = 0; L < NLA; ++L) STG_A(L, 1, 1);
#pragma unroll
    for (int L = 0; L < NLB; ++L) STG_B(L, 1, 1);
    if constexpr (NL == 7) asm volatile("s_waitcnt vmcnt(7)" ::: "memory");
    else                   asm volatile("s_waitcnt vmcnt(6)" ::: "memory");
    asm volatile("s_barrier" ::: "memory");

    // read-side swizzle: frag row = 16*frag + l15 -> row&7 == l15&7
    const int c0x = (q4 * 16) ^ ((l15 & 7) << 4);
    const int c1x = c0x ^ 64;

    f32x4 acc[WM][WN] = {};
    bf8 breg[WN][2];

#pragma unroll 1
    for (int t = 0; t < NT; ++t) {
        const int cur = t & 1;
        const char* ldsA = (const char*)&lds[cur][0];
        const char* ldsB = ldsA + BM * 128;
#pragma unroll
        for (int p = 0; p < 4; ++p) {
            // stage tile t+2 into the regions of buf[cur] that died last phase
            if (p == 1 && t < NT - 2) {
#pragma unroll
                for (int L = 0; L < NLB; ++L) STG_B(L, t + 2, cur);
            }
            if constexpr (BM == 256) {
                // A lines 0,2 (rows 0-63 of each wm-half) are read only in p0/p1
                if (p == 2 && t < NT - 2) {
                    STG_A(0, t + 2, cur);
                    STG_A(2, t + 2, cur);
                }
            }
            bf8 areg[MP][2];
#pragma unroll
            for (int j = 0; j < MP; ++j) {
                const char* rp = ldsA + (wm * (BM / 2) + (p * MP + j) * 16 + l15) * 128;
                areg[j][0] = *(const bf8*)(rp + c0x);
                areg[j][1] = *(const bf8*)(rp + c1x);
            }
            if (p == 0) {
#pragma unroll
                for (int nf = 0; nf < WN; ++nf) {
                    const char* rp = ldsB + (wn * (WN * 16) + nf * 16 + l15) * 128;
                    breg[nf][0] = *(const bf8*)(rp + c0x);
                    breg[nf][1] = *(const bf8*)(rp + c1x);
                }
            }
            asm volatile("s_barrier" ::: "memory");
            asm volatile("s_waitcnt lgkmcnt(0)" ::: "memory");
            __builtin_amdgcn_s_setprio(1);
#pragma unroll
            for (int j = 0; j < MP; ++j)
#pragma unroll
                for (int nf = 0; nf < WN; ++nf)
#pragma unroll
                    for (int ks = 0; ks < 2; ++ks)
                        acc[p * MP + j][nf] = __builtin_amdgcn_mfma_f32_16x16x32_bf16(
                            areg[j][ks], breg[nf][ks], acc[p * MP + j][nf], 0, 0, 0);
            __builtin_amdgcn_s_setprio(0);
            asm volatile("s_barrier" ::: "memory");
        }
        // boundary: stage the A lines that stayed live through p3, then counted
        // vmcnt -- guarantees tile t+1 (issued during t-1) fully landed, while
        // tile t+2's NL loads stay in flight across the barrier.
        if (t < NT - 2) {
            if constexpr (BM == 256) { STG_A(1, t + 2, cur); STG_A(3, t + 2, cur); }
            else                     { STG_A(0, t + 2, cur); STG_A(1, t + 2, cur); }
            if constexpr (NL == 7) asm volatile("s_waitcnt vmcnt(7)" ::: "memory");
            else                   asm volatile("s_waitcnt vmcnt(6)" ::: "memory");
        } else if (t == NT - 2) {
            asm volatile("s_waitcnt vmcnt(0)" ::: "memory");
        }
        asm volatile("s_barrier" ::: "memory");
    }
#undef STG_A
#undef STG_B

    const int rowb = bm * BM + wm * (BM / 2);
    const int colb = bn * BN + wn * (WN * 16);
#pragma unroll
    for (int mf = 0; mf < WM; ++mf)
#pragma unroll
        for (int nf = 0; nf < WN; ++nf)
#pragma unroll
            for (int r = 0; r < 4; ++r) {
                const int row = rowb + mf * 16 + q4 * 4 + r;
                const int col = colb + nf * 16 + l15;
                if constexpr (MODE == 0)
                    Cbf[(size_t)row * CSTR + col] = f2bf(acc[mf][nf][r]);
                else
                    Cf[(size_t)row * CSTR + col] = acc[mf][nf][r];
            }
}

// ---------------- flash attention ----------------
// grid: 512 = 16 q-tiles * 32 heads. block 256 = 4 waves, each wave owns 32 Q rows.
// No running max (scores bounded: |s|<~20 -> exp2 stays in fp32/bf16 range), so
// softmax = unnormalized p=exp2(s*cs), per-lane row-sum accumulated in registers,
// single shuffle-reduce + normalize at the end.
#define PSTR 72   // P row stride in shorts: 64 cols + 8 pad (2-way bank alias = free)
__global__ __launch_bounds__(256) void attn_kernel(const u16* __restrict__ xqkv,
                                                   const u16* __restrict__ vt,
                                                   u16* __restrict__ aw) {
    // smem layout (shorts): [0,8192) K [4][64][32]; [8192,16384) V [2][128][32];
    // [16384,16384+128*PSTR) P [128][PSTR].  Q staged once at [0,16384) then reused.
    __shared__ __align__(16) u16 sm[16384 + 128 * PSTR];
    const int tid = threadIdx.x, w = tid >> 6, l = tid & 63, l15 = l & 15, q4 = l >> 4;
    const int qh = blockIdx.x & 31;
    const int qslot = blockIdx.x >> 5;
    // complementary pairing: blocks b and b+256 get qt summing to 15 (tail balance)
    const int qt = (qslot < 8) ? qslot : 23 - qslot;
    const int kh = qh >> 2;

    { // stage Q tile: [ks=w][row 128][32], async
        const u16* gq = xqkv + (size_t)(qt * 128 + (l >> 2)) * DQKV + qh * HD + w * 32 + (l & 3) * 8;
#pragma unroll
        for (int i = 0; i < 8; ++i)
            GLOAD_LDS16(gq + (size_t)i * 16 * DQKV, &sm[w * 4096 + i * 512]);
    }
    __syncthreads();
    bf8 qf[4][2];
#pragma unroll
    for (int ks = 0; ks < 4; ++ks)
#pragma unroll
        for (int mt = 0; mt < 2; ++mt)
            qf[ks][mt] = *(const bf8*)&sm[ks * 4096 + (w * 32 + mt * 16 + l15) * 32 + q4 * 8];
    __syncthreads();

    f32x4 O[2][8] = {};
    float plrow[2][4] = {};   // per-lane unnormalized row-sum partials

    u16* ldsK = sm;
    u16* ldsV = sm + 8192;
    u16* ldsP = sm + 16384;
    const int nkt = 2 * qt + 2;
    const float cs = 0.12751744f; // (1/sqrt(128)) * log2(e)

    const u16* gk_base = xqkv + (32 + kh) * HD + w * 32 + (l & 3) * 8;
    const u16* gv_base = vt + (size_t)kh * HD * SEQ + (size_t)((w & 1) * 64 + (l >> 2)) * SEQ + (w >> 1) * 32 + (l & 3) * 8;

    for (int kt = 0; kt < nkt; ++kt) {
        { // stage K: wave w owns k-chunk ks=w  (async, lane-contiguous)
            const u16* gk = gk_base + (size_t)(kt * 64 + (l >> 2)) * DQKV;
#pragma unroll
            for (int i = 0; i < 4; ++i)
                GLOAD_LDS16(gk + (size_t)i * 16 * DQKV, ldsK + w * 2048 + i * 512);
        }
        { // stage V^T: wave w owns pk=w>>1, d-half=(w&1)*64
            const u16* gv = gv_base + kt * 64;
#pragma unroll
            for (int i = 0; i < 4; ++i)
                GLOAD_LDS16(gv + (size_t)i * 16 * SEQ, ldsV + (w >> 1) * 4096 + (w & 1) * 2048 + i * 512);
        }
        __syncthreads();   // drains vmcnt

        // S = Q K^T
        f32x4 S[2][4] = {};
#pragma unroll
        for (int ks = 0; ks < 4; ++ks) {
            bf8 kf[4];
#pragma unroll
            for (int nt = 0; nt < 4; ++nt)
                kf[nt] = *(const bf8*)&ldsK[ks * 2048 + (nt * 16 + l15) * 32 + q4 * 8];
#pragma unroll
            for (int mt = 0; mt < 2; ++mt)
#pragma unroll
                for (int nt = 0; nt < 4; ++nt)
                    S[mt][nt] = __builtin_amdgcn_mfma_f32_16x16x32_bf16(qf[ks][mt], kf[nt], S[mt][nt], 0, 0, 0);
        }

        const bool domask = (kt >= 2 * qt);
#pragma unroll
        for (int mt = 0; mt < 2; ++mt)
#pragma unroll
            for (int r = 0; r < 4; ++r) {
                const int row = qt * 128 + w * 32 + mt * 16 + q4 * 4 + r;
#pragma unroll
                for (int nt = 0; nt < 4; ++nt) {
                    float t = S[mt][nt][r] * cs;
                    if (domask && (kt * 64 + nt * 16 + l15 > row)) t = -1e30f;
                    float p = exp2f(t);
                    plrow[mt][r] += p;
                    ldsP[(w * 32 + mt * 16 + q4 * 4 + r) * PSTR + nt * 16 + l15] = f2bf(p);
                }
            }

        // O += P V   (P rows are wave-private: no barrier needed)
#pragma unroll
        for (int pk = 0; pk < 2; ++pk) {
            bf8 pf[2], vf[8];
#pragma unroll
            for (int mt = 0; mt < 2; ++mt)
                pf[mt] = *(const bf8*)&ldsP[(w * 32 + mt * 16 + l15) * PSTR + pk * 32 + q4 * 8];
#pragma unroll
            for (int nt = 0; nt < 8; ++nt)
                vf[nt] = *(const bf8*)&ldsV[pk * 4096 + (nt * 16 + l15) * 32 + q4 * 8];
#pragma unroll
            for (int mt = 0; mt < 2; ++mt)
#pragma unroll
                for (int nt = 0; nt < 8; ++nt)
                    O[mt][nt] = __builtin_amdgcn_mfma_f32_16x16x32_bf16(pf[mt], vf[nt], O[mt][nt], 0, 0, 0);
        }
        __syncthreads();   // all waves done reading K/V/P before next stage
    }

#pragma unroll
    for (int mt = 0; mt < 2; ++mt)
#pragma unroll
        for (int r = 0; r < 4; ++r) {
            float ls = plrow[mt][r];   // row-sum lives across the 16 lanes of this q4 group
#pragma unroll
            for (int off = 1; off <= 8; off <<= 1)
                ls += __shfl_xor(ls, off, 64);
            const float linv = 1.0f / ls;
            const int row = qt * 128 + w * 32 + mt * 16 + q4 * 4 + r;
#pragma unroll
            for (int nt = 0; nt < 8; ++nt)
                aw[(size_t)row * 4096 + qh * HD + nt * 16 + l15] = f2bf(O[mt][nt][r] * linv);
        }
}

// ---------------- launch ----------------

extern "C" void kernel_launch(void* const* d_in, const int* in_sizes, int n_in,
                              void* d_out, int out_size, void* d_ws, size_t ws_size,
                              hipStream_t stream) {
    const float* hs = (const float*)d_in[0];
    const float* wqkv = (const float*)d_in[1];
    const float* wo = (const float*)d_in[2];
    float* out = (float*)d_out;

    char* ws = (char*)d_ws;
    const size_t oHbf = 0;
    const size_t oWqkvT = oHbf + (size_t)SEQ * HIDDEN * 2;          // 16.78 MB
    const size_t oWoT = oWqkvT + (size_t)DQKV * HIDDEN * 2;         // +50.33 MB
    const size_t oXQKV = oWoT + (size_t)HIDDEN * HIDDEN * 2;        // +33.55 MB
    const size_t oVT = oXQKV + (size_t)SEQ * DQKV * 2;              // +25.17 MB
    const size_t oAW = oVT + (size_t)8 * HD * SEQ * 2;              // +4.19 MB
    const size_t total = oAW + (size_t)SEQ * HIDDEN * 2;            // +16.78 MB = 146.8 MB
    if (ws_size < total) return;

    u16* Hbf = (u16*)(ws + oHbf);
    u16* WqkvT = (u16*)(ws + oWqkvT);
    u16* WoT = (u16*)(ws + oWoT);
    u16* XQKV = (u16*)(ws + oXQKV);
    u16* VT = (u16*)(ws + oVT);
    u16* AW = (u16*)(ws + oAW);

    convert_bf16_kernel<<<(SEQ * HIDDEN) / 1024, 256, 0, stream>>>(hs, Hbf);
    transpose_w_kernel<<<(HIDDEN / 64) * (DQKV / 64), 256, 0, stream>>>(wqkv, WqkvT, HIDDEN, DQKV);
    transpose_w_kernel<<<(HIDDEN / 64) * (HIDDEN / 64), 256, 0, stream>>>(wo, WoT, HIDDEN, HIDDEN);
    gemm8p_kernel<256, 192, 0><<<256, 512, 0, stream>>>(Hbf, WqkvT, XQKV, nullptr);  // 8x32 grid
    rope_kernel<<<SEQ * 10, 256, 0, stream>>>(XQKV);
    transpose_v_kernel<<<8 * 64, 256, 0, stream>>>(XQKV, VT);
    attn_kernel<<<512, 256, 0, stream>>>(XQKV, VT, AW);
    gemm8p_kernel<128, 256, 1><<<256, 512, 0, stream>>>(AW, WoT, nullptr, out);      // 16x16 grid
}